// Round 2
// baseline (127.762 us; speedup 1.0000x reference)
//
#include <hip/hip_runtime.h>
#include <math.h>

#define SLOPE 0.1f
#define B_ 16
#define C_ 64
#define H_ 160
#define W_ 160
#define HW_ (H_*W_)

// ws layout (floats):
//   [0, 9216)        k[b][c][9]
//   [9216, 10240)    att[b][c]
//   [10240, 14336)   WcT[c][o]  (transposed Wc)
#define WS_K   0
#define WS_ATT 9216
#define WS_WCT 10240

__device__ __forceinline__ float lrelu(float x) { return fmaxf(x, SLOPE * x); }

__global__ __launch_bounds__(64) void prep_kernel(
    const float* __restrict__ deg,
    const float* __restrict__ W1,
    const float* __restrict__ W2,
    const float* __restrict__ Wc,
    const float* __restrict__ Wd1,
    const float* __restrict__ Wd2,
    float* __restrict__ ws) {
  const int b = blockIdx.x;   // 0..15
  const int j = threadIdx.x;  // 0..63
  __shared__ float sd[64], sh[64], sa[8];
  sd[j] = deg[b * 64 + j];
  __syncthreads();

  float acc = 0.f;
  for (int i = 0; i < 64; ++i) acc = fmaf(sd[i], W1[j * 64 + i], acc);
  sh[j] = lrelu(acc);

  if (j < 8) {
    float s = 0.f;
    for (int i = 0; i < 64; ++i) s = fmaf(sd[i], Wd1[j * 64 + i], s);
    sa[j] = lrelu(s);
  }
  __syncthreads();

  float kv[9];
#pragma unroll
  for (int t = 0; t < 9; ++t) kv[t] = 0.f;
  for (int l = 0; l < 64; ++l) {
    float hl = sh[l];
#pragma unroll
    for (int t = 0; t < 9; ++t) kv[t] = fmaf(hl, W2[(j * 9 + t) * 64 + l], kv[t]);
  }
#pragma unroll
  for (int t = 0; t < 9; ++t) ws[WS_K + (b * 64 + j) * 9 + t] = kv[t];

  float s2 = 0.f;
#pragma unroll
  for (int r = 0; r < 8; ++r) s2 = fmaf(Wd2[j * 8 + r], sa[r], s2);
  ws[WS_ATT + b * 64 + j] = 1.f / (1.f + __expf(-s2));

  if (b == 0) {
    for (int c = 0; c < 64; ++c) ws[WS_WCT + c * 64 + j] = Wc[j * 64 + c];
  }
}

// 12 masked tap values covering a horizontal pixel pair (xb, xb+1):
// rows y-1 (t), y (c), y+1 (b); cols xb-1 (m1), xb, xb+1 (float2), xb+2 (p2).
struct Taps {
  float tfx, tfy, cfx, cfy, bfx, bfy;
  float tm1, tp2, cm1, cp2, bm1, bp2;
};

__device__ __forceinline__ Taps load_taps(
    const float* __restrict__ p, int o_m, int o_c, int o_p,
    int xb, int xm1, int xp2,
    float mt, float mb, float ml, float mr,
    float mtl, float mtr, float mbl, float mbr) {
  Taps t;
  const float2 a = *(const float2*)(p + o_m + xb);
  const float2 m = *(const float2*)(p + o_c + xb);
  const float2 z = *(const float2*)(p + o_p + xb);
  const float v_tm1 = p[o_m + xm1];
  const float v_tp2 = p[o_m + xp2];
  const float v_cm1 = p[o_c + xm1];
  const float v_cp2 = p[o_c + xp2];
  const float v_bm1 = p[o_p + xm1];
  const float v_bp2 = p[o_p + xp2];
  t.tfx = a.x * mt;  t.tfy = a.y * mt;
  t.cfx = m.x;       t.cfy = m.y;       // center row/cols always valid
  t.bfx = z.x * mb;  t.bfy = z.y * mb;
  t.tm1 = v_tm1 * mtl; t.tp2 = v_tp2 * mtr;
  t.cm1 = v_cm1 * ml;  t.cp2 = v_cp2 * mr;
  t.bm1 = v_bm1 * mbl; t.bp2 = v_bp2 * mbr;
  return t;
}

// Block = 128 threads = 8 rows x 16 thread-cols; each thread owns a pixel
// PAIR (xb, xb+1) -> tile 8 rows x 32 cols. acc0/acc1[64] output channels
// in registers. c-loop descends so the store-time residual re-read (o
// ascending) starts on L2-warm channels.
__global__ __launch_bounds__(128, 2) void main_kernel(
    const float* __restrict__ feat,
    const float* __restrict__ bc,
    const float* __restrict__ ws,
    float* __restrict__ out) {
  const int tx = blockIdx.x;  // 0..4
  const int ty = blockIdx.y;  // 0..19
  const int b  = blockIdx.z;  // 0..15
  const int lx = threadIdx.x & 15;
  const int ly = threadIdx.x >> 4;
  const int xb = tx * 32 + lx * 2;
  const int y  = ty * 8 + ly;

  const float* __restrict__ kkp = ws + WS_K + b * 576;  // uniform -> s_load
  const float* __restrict__ att = ws + WS_ATT + b * 64; // uniform -> s_load
  const float* __restrict__ wct = ws + WS_WCT;          // uniform -> s_load

  const int ym1 = max(y - 1, 0), yp1 = min(y + 1, H_ - 1);
  const int o_m = ym1 * W_, o_c = y * W_, o_p = yp1 * W_;
  const int xm1 = max(xb - 1, 0);
  const int xp2 = min(xb + 2, W_ - 1);
  const float mt = (y > 0) ? 1.f : 0.f;
  const float mb = (y < H_ - 1) ? 1.f : 0.f;
  const float ml = (xb > 0) ? 1.f : 0.f;
  const float mr = (xb + 2 < W_) ? 1.f : 0.f;
  const float mtl = mt * ml, mtr = mt * mr, mbl = mb * ml, mbr = mb * mr;

  float acc0[64], acc1[64];
#pragma unroll
  for (int o = 0; o < 64; ++o) {
    const float bv = bc[o];
    acc0[o] = bv;
    acc1[o] = bv;
  }

  const float* __restrict__ plane = feat + (size_t)(b * 64) * HW_;

  // Descending channel loop with next-channel tap prefetch.
  Taps cur = load_taps(plane + 63 * HW_, o_m, o_c, o_p, xb, xm1, xp2,
                       mt, mb, ml, mr, mtl, mtr, mbl, mbr);
  for (int ci = 0; ci < 64; ++ci) {
    const int c = 63 - ci;
    Taps nxt = cur;
    if (c > 0) {
      nxt = load_taps(plane + (c - 1) * HW_, o_m, o_c, o_p, xb, xm1, xp2,
                      mt, mb, ml, mr, mtl, mtr, mbl, mbr);
    }
    const float* __restrict__ kc = kkp + c * 9;
    const float k0 = kc[0], k1 = kc[1], k2 = kc[2];
    const float k3 = kc[3], k4 = kc[4], k5 = kc[5];
    const float k6 = kc[6], k7 = kc[7], k8 = kc[8];

    float s0 = cur.tm1 * k0;
    s0 = fmaf(cur.tfx, k1, s0); s0 = fmaf(cur.tfy, k2, s0);
    s0 = fmaf(cur.cm1, k3, s0); s0 = fmaf(cur.cfx, k4, s0);
    s0 = fmaf(cur.cfy, k5, s0); s0 = fmaf(cur.bm1, k6, s0);
    s0 = fmaf(cur.bfx, k7, s0); s0 = fmaf(cur.bfy, k8, s0);

    float s1 = cur.tfx * k0;
    s1 = fmaf(cur.tfy, k1, s1); s1 = fmaf(cur.tp2, k2, s1);
    s1 = fmaf(cur.cfx, k3, s1); s1 = fmaf(cur.cfy, k4, s1);
    s1 = fmaf(cur.cp2, k5, s1); s1 = fmaf(cur.bfx, k6, s1);
    s1 = fmaf(cur.bfy, k7, s1); s1 = fmaf(cur.bp2, k8, s1);

    const float tv0 = lrelu(s0);
    const float tv1 = lrelu(s1);

    const float* __restrict__ wc = wct + c * 64;
#pragma unroll
    for (int o = 0; o < 64; ++o) {
      const float w = wc[o];  // uniform -> SGPR operand
      acc0[o] = fmaf(w, tv0, acc0[o]);
      acc1[o] = fmaf(w, tv1, acc1[o]);
    }
    cur = nxt;
  }

  // Store + residual (re-read feat center pair per output channel).
  const int pix = o_c + xb;
  const float* __restrict__ inp = plane + pix;
  float* __restrict__ outp = out + (size_t)(b * 64) * HW_ + pix;
#pragma unroll
  for (int o = 0; o < 64; ++o) {
    const float2 f = *(const float2*)(inp + (size_t)o * HW_);
    const float a = att[o];
    float2 r;
    r.x = fmaf(f.x, a, acc0[o]);
    r.y = fmaf(f.y, a, acc1[o]);
    *(float2*)(outp + (size_t)o * HW_) = r;
  }
}

extern "C" void kernel_launch(void* const* d_in, const int* in_sizes, int n_in,
                              void* d_out, int out_size, void* d_ws, size_t ws_size,
                              hipStream_t stream) {
  const float* feat = (const float*)d_in[0];
  const float* deg  = (const float*)d_in[1];
  const float* W1   = (const float*)d_in[2];
  const float* W2   = (const float*)d_in[3];
  const float* Wc   = (const float*)d_in[4];
  const float* bc   = (const float*)d_in[5];
  const float* Wd1  = (const float*)d_in[6];
  const float* Wd2  = (const float*)d_in[7];
  float* out = (float*)d_out;
  float* ws  = (float*)d_ws;

  prep_kernel<<<dim3(B_), dim3(64), 0, stream>>>(deg, W1, W2, Wc, Wd1, Wd2, ws);
  main_kernel<<<dim3(5, 20, B_), dim3(128), 0, stream>>>(feat, bc, ws, out);
}